// Round 2
// baseline (189.177 us; speedup 1.0000x reference)
//
#include <hip/hip_runtime.h>
#include <hip/hip_bf16.h>
#include <stdint.h>

// QuantizedConv2d int8: x (32,128,56,56), w (256,128,3,3), pad 1, stride 1.
// Implicit GEMM on v_mfma_i32_32x32x32_i8. M=out-ch, N=pixels, K=9*128=1152.
// R11: ZERO-BARRIER K-loop. Weights (64-ch slice, all 9 taps, 72 KB) LDS-
// resident, staged once. B operands read DIRECTLY from global (xp repacked
// [n][row][cc(8)][px(58)][16] so loads are coalesced 512B segments); x is
// L2/L3-resident. LDS 74 KB -> 2 blocks x 8 waves = 16 waves/CU (4/SIMD,
// 128-VGPR cap) -- 2x the wave count of R9/R10, no per-tap barrier convoy.
// Grid (rg, n, kt-slowest): kt-siblings land on the same XCD -> x rows stay
// hot in that XCD's L2 across all 4 kt rounds.

#define NB   32
#define CIN  128
#define HO   56
#define WO   56
#define KOUT 256
#define HP   58
#define ROWB (HP * CIN)          // 7424 bytes per padded row (8 cc-planes x 928)

typedef int v4i  __attribute__((ext_vector_type(4)));
typedef int v16i __attribute__((ext_vector_type(16)));

static __device__ __forceinline__ void gload_lds16(const int8_t* g, int8_t* l) {
  __builtin_amdgcn_global_load_lds(
      (const __attribute__((address_space(1))) void*)g,
      (__attribute__((address_space(3))) void*)l, 16, 0, 0);
}

// ------ pack x: NCHW int32 -> padded [n][row][cc(8)][px(58)][16B] int8 ------
__global__ __launch_bounds__(256) void pack_x_kernel(const int* __restrict__ x,
                                                     int8_t* __restrict__ xp) {
  __shared__ int t32[128][57];       // 29,184 B, stride 57 to break conflicts
  const int tid = threadIdx.x;
  const int r = blockIdx.x;          // padded row 0..57
  const int n = blockIdx.y;
  const bool interior = (r >= 1) && (r <= HO);

  if (interior) {
    const int h = r - 1;
    const int* xrow = x + ((size_t)(n * CIN) * HO + h) * WO;  // c stride = 3136 ints
    #pragma unroll
    for (int it = 0; it < 7; ++it) {
      const int j = it * 256 + tid;  // < 1792 = 128 c x 14 w-quads
      const int c = j / 14;
      const int w4 = j - c * 14;
      const int4 v = *reinterpret_cast<const int4*>(xrow + c * 3136 + w4 * 4);
      t32[c][w4 * 4 + 0] = v.x;
      t32[c][w4 * 4 + 1] = v.y;
      t32[c][w4 * 4 + 2] = v.z;
      t32[c][w4 * 4 + 3] = v.w;
    }
  }
  __syncthreads();
  // write: word (n, r, cc, w, wi) <- channels cc*16+wi*4 .. +3 at padded col w
  #pragma unroll
  for (int it = 0; it < 8; ++it) {
    const int i = it * 256 + tid;
    if (i < HP * 32) {               // 1856 words per row
      const int wi = i & 3;
      const int w = (i >> 2) % HP;
      const int cc = (i >> 2) / HP;  // 0..7
      const int c4 = cc * 4 + wi;    // channel-word 0..31
      int vv = 0;
      if (interior && w >= 1 && w <= WO) {
        const int b0 = t32[c4 * 4 + 0][w - 1] & 0xff;
        const int b1 = t32[c4 * 4 + 1][w - 1] & 0xff;
        const int b2 = t32[c4 * 4 + 2][w - 1] & 0xff;
        const int b3 = t32[c4 * 4 + 3][w - 1];
        vv = b0 | (b1 << 8) | (b2 << 16) | (b3 << 24);
      }
      *reinterpret_cast<int*>(
          xp + ((size_t)(n * HP + r) * 8 + cc) * 928 + w * 16 + wi * 4) = vv;
    }
  }
}

// ------ pack w: OIHW int32 -> [kt(4)][tap(9)][cc(8)][ch(64)] 16B chunks ------
__global__ __launch_bounds__(256) void pack_w_kernel(const int* __restrict__ wgt,
                                                     int8_t* __restrict__ wq) {
  const int wid = blockIdx.x * 256 + threadIdx.x;   // 0..73727 int32 words
  const int wi = wid & 3;
  const int ci = wid >> 2;                          // chunk 0..18431
  const int kt = ci / 4608;                         // 4608 = 9*8*64
  const int r  = ci - kt * 4608;
  const int tap = r >> 9;                           // 512 = 8*64
  const int r2  = r & 511;
  const int cc  = r2 >> 6;
  const int ch  = r2 & 63;
  const int k_global = kt * 64 + ch;
  const int cin0 = cc * 16 + wi * 4;
  const int base = (k_global * CIN + cin0) * 9 + tap;  // OIHW, 3x3=9 taps
  const int v0 = wgt[base];
  const int v1 = wgt[base + 9];
  const int v2 = wgt[base + 18];
  const int v3 = wgt[base + 27];
  reinterpret_cast<int*>(wq)[wid] =
      (v0 & 0xff) | ((v1 & 0xff) << 8) | ((v2 & 0xff) << 16) | (v3 << 24);
}

// ---------------- conv: zero-barrier K-loop, B from global ----------------
// grid (7 rg, 32 n, 4 kt) = 896 blocks, 512 threads = 8 waves (1 row each).
// Block: 64 out-ch x 8 output rows. Wave wr: row h0+wr, 64 ch x 64 px.
// Per ks: 2 LDS A-reads (conflict-free) + 2 coalesced global B-reads -> 4 MFMA.
// No barriers after the weight stage; 16 waves/CU free-run.
__global__ __launch_bounds__(512, 4) void conv_kernel(const int8_t* __restrict__ xp,
                                                      const int8_t* __restrict__ wq,
                                                      const int* __restrict__ bias,
                                                      const float* __restrict__ wscale,
                                                      int* __restrict__ out) {
  __shared__ __align__(16) int8_t lw[9 * 8 * 64 * 16];   // 73,728 B: all taps
  __shared__ int   bsh[64];
  __shared__ float ssh[64];

  const int tid = threadIdx.x;
  const int rg = blockIdx.x;           // row group 0..6
  const int n_img = blockIdx.y;
  const int kt = blockIdx.z;           // 64-ch slice, slowest -> L2 reuse of xp
  const int h0 = rg * 8;

  const int lane = tid & 63;
  const int wr = tid >> 6;             // wave = output row 0..7
  const int p0 = lane & 31;
  const int half = lane >> 5;

  // ---- stage weights: 4608 chunks, linear (layout pre-swizzled by pack_w) ----
  const int8_t* wqt = wq + (size_t)kt * 73728;
  #pragma unroll
  for (int it = 0; it < 9; ++it) {
    const int j = it * 512 + tid;
    gload_lds16(wqt + j * 16, lw + j * 16);
  }
  if (tid < 64) {
    const int ch = kt * 64 + tid;
    bsh[tid] = bias[ch];
    ssh[tid] = (0.02f * wscale[ch]) / 0.05f;   // IN_SCALE * ws / OUT_SCALE
  }
  __syncthreads();

  v16i acc[2][2];                      // [mt: 32-ch tile][nt: 32-px tile]
  #pragma unroll
  for (int mt = 0; mt < 2; ++mt)
    #pragma unroll
    for (int nt = 0; nt < 2; ++nt)
      #pragma unroll
      for (int e = 0; e < 16; ++e) acc[mt][nt][e] = 0;

  // B base: this wave's row, lane's pixel. Layout [row][cc][px][16].
  const int8_t* xb = xp + ((size_t)(n_img * HP + h0 + wr) * 8) * 928 + p0 * 16;

  #pragma unroll 1
  for (int tap = 0; tap < 9; ++tap) {
    const int kh = (tap >= 3) + (tap >= 6);
    const int kw = tap - 3 * kh;
    const int8_t* lwt = lw + tap * 8192;          // [cc(8)][ch(64)] chunk-major
    const int8_t* xrow = xb + (kh * 8) * 928 + kw * 16;
    #pragma unroll
    for (int ks = 0; ks < 4; ++ks) {
      const int cch = 2 * ks + half;              // k-chunk for this lane
      const v4i a0 = *reinterpret_cast<const v4i*>(lwt + cch * 1024 + p0 * 16);
      const v4i a1 = *reinterpret_cast<const v4i*>(lwt + cch * 1024 + p0 * 16 + 512);
      const v4i b0 = *reinterpret_cast<const v4i*>(xrow + cch * 928);
      const v4i b1 = *reinterpret_cast<const v4i*>(xrow + cch * 928 + 512);
      // OOB px (beyond col 57) only feeds epilogue-masked columns (w >= 56).
      acc[0][0] = __builtin_amdgcn_mfma_i32_32x32x32_i8(a0, b0, acc[0][0], 0, 0, 0);
      acc[1][0] = __builtin_amdgcn_mfma_i32_32x32x32_i8(a1, b0, acc[1][0], 0, 0, 0);
      acc[0][1] = __builtin_amdgcn_mfma_i32_32x32x32_i8(a0, b1, acc[0][1], 0, 0, 0);
      acc[1][1] = __builtin_amdgcn_mfma_i32_32x32x32_i8(a1, b1, acc[1][1], 0, 0, 0);
    }
  }

  // ---- epilogue: D row = ch = mt*32 + (r&3)+8*(r>>2)+4*half, col = pixel ----
  const int h = h0 + wr;
  #pragma unroll
  for (int mt = 0; mt < 2; ++mt) {
    #pragma unroll
    for (int r = 0; r < 16; ++r) {
      const int cl = mt * 32 + (r & 3) + 8 * (r >> 2) + 4 * half;
      const int bi = bsh[cl];
      const float sc = ssh[cl];
      int* ob = out + (((size_t)(n_img * KOUT + kt * 64 + cl)) * HO + h) * WO;
      #pragma unroll
      for (int nt = 0; nt < 2; ++nt) {
        const int w = nt * 32 + p0;
        if (w < WO) {
          float v = (float)(acc[mt][nt][r] + bi) * sc;
          v = rintf(v);                          // round-half-even == jnp.round
          v = fminf(fmaxf(v, -128.0f), 127.0f);
          ob[w] = (int)v;
        }
      }
    }
  }
}

extern "C" void kernel_launch(void* const* d_in, const int* in_sizes, int n_in,
                              void* d_out, int out_size, void* d_ws, size_t ws_size,
                              hipStream_t stream) {
  const int* x = (const int*)d_in[0];
  const int* wgt = (const int*)d_in[1];
  const int* bias = (const int*)d_in[2];
  const float* wscale = (const float*)d_in[3];
  int* out = (int*)d_out;

  int8_t* xp = (int8_t*)d_ws;                               // 13,780,992 B
  int8_t* wq = (int8_t*)d_ws + (size_t)NB * HP * ROWB;      // 294,912 B

  pack_x_kernel<<<dim3(HP, NB), 256, 0, stream>>>(x, xp);
  pack_w_kernel<<<288, 256, 0, stream>>>(wgt, wq);
  conv_kernel<<<dim3(7, 32, 4), 512, 0, stream>>>(xp, wq, bias, wscale, out);
}

// Round 3
// 182.899 us; speedup vs baseline: 1.0343x; 1.0343x over previous
//
#include <hip/hip_runtime.h>
#include <hip/hip_bf16.h>
#include <stdint.h>

// QuantizedConv2d int8: x (32,128,56,56), w (256,128,3,3), pad 1, stride 1.
// Implicit GEMM on v_mfma_i32_32x32x32_i8. M=out-ch, N=pixels, K=9*128=1152.
// R12: B-in-LDS (staged once, 44.5 KB, XOR swizzle) + per-tap A double-buffer
// (2x16 KB, 128-ch slice) = 79.3 KB LDS -> 2 blocks x 8 waves = 16 waves/CU
// (4/SIMD). VMEM per block ~78 KB (vs R11's 650 KB global-B), LDS pipe ~23 us
// over the run, MFMA 15.3 us. One barrier per tap; two co-resident blocks
// cover each other's drain. Block tile 128ch x 4 rows; wave 64ch x 64px.

#define NB   32
#define CIN  128
#define HO   56
#define WO   56
#define KOUT 256
#define HP   58
#define ROWB (HP * CIN)          // 7424 bytes per padded row

typedef int v4i  __attribute__((ext_vector_type(4)));
typedef int v16i __attribute__((ext_vector_type(16)));

static __device__ __forceinline__ void gload_lds16(const int8_t* g, int8_t* l) {
  __builtin_amdgcn_global_load_lds(
      (const __attribute__((address_space(1))) void*)g,
      (__attribute__((address_space(3))) void*)l, 16, 0, 0);
}

// ---------------- pack x: NCHW int32 -> padded NHWC int8 (int4 reads) --------
__global__ __launch_bounds__(256) void pack_x_kernel(const int* __restrict__ x,
                                                     int8_t* __restrict__ xp) {
  __shared__ int t32[128][57];       // 29,184 B, stride 57 to break conflicts
  const int tid = threadIdx.x;
  const int r = blockIdx.x;          // padded row 0..57
  const int n = blockIdx.y;
  const bool interior = (r >= 1) && (r <= HO);

  if (interior) {
    const int h = r - 1;
    const int* xrow = x + ((size_t)(n * CIN) * HO + h) * WO;  // c stride = 3136 ints
    #pragma unroll
    for (int it = 0; it < 7; ++it) {
      const int j = it * 256 + tid;  // < 1792 = 128 c x 14 w-quads
      const int c = j / 14;
      const int w4 = j - c * 14;
      const int4 v = *reinterpret_cast<const int4*>(xrow + c * 3136 + w4 * 4);
      t32[c][w4 * 4 + 0] = v.x;
      t32[c][w4 * 4 + 1] = v.y;
      t32[c][w4 * 4 + 2] = v.z;
      t32[c][w4 * 4 + 3] = v.w;
    }
  }
  __syncthreads();
  #pragma unroll
  for (int it = 0; it < 8; ++it) {
    const int i = it * 256 + tid;
    if (i < HP * 32) {
      const int w = i >> 5;          // padded col 0..57
      const int c4 = i & 31;
      int vv = 0;
      if (interior && w >= 1 && w <= WO) {
        const int b0 = t32[c4 * 4 + 0][w - 1] & 0xff;
        const int b1 = t32[c4 * 4 + 1][w - 1] & 0xff;
        const int b2 = t32[c4 * 4 + 2][w - 1] & 0xff;
        const int b3 = t32[c4 * 4 + 3][w - 1];
        vv = b0 | (b1 << 8) | (b2 << 16) | (b3 << 24);
      }
      *reinterpret_cast<int*>(xp + ((size_t)(n * HP + r) * HP + w) * CIN + c4 * 4) = vv;
    }
  }
}

// ---- pack w: OIHW int32 -> [ktb(2)][tap(9)][cc(8)][ch(128)] 16B chunks ------
__global__ __launch_bounds__(256) void pack_w_kernel(const int* __restrict__ wgt,
                                                     int8_t* __restrict__ wq) {
  const int wid = blockIdx.x * 256 + threadIdx.x;   // 0..73727 int32 words
  const int wi = wid & 3;
  const int ci = wid >> 2;                          // chunk 0..18431
  const int ktb = ci / 9216;                        // 9216 = 9*8*128
  const int r  = ci - ktb * 9216;
  const int tap = r >> 10;                          // 1024 = 8*128
  const int r2  = r & 1023;
  const int cc  = r2 >> 7;
  const int ch  = r2 & 127;
  const int k_global = ktb * 128 + ch;
  const int cin0 = cc * 16 + wi * 4;
  const int base = (k_global * CIN + cin0) * 9 + tap;  // OIHW, 3x3=9 taps
  const int v0 = wgt[base];
  const int v1 = wgt[base + 9];
  const int v2 = wgt[base + 18];
  const int v3 = wgt[base + 27];
  reinterpret_cast<int*>(wq)[wid] =
      (v0 & 0xff) | ((v1 & 0xff) << 8) | ((v2 & 0xff) << 16) | (v3 << 24);
}

// ------- conv: B-in-LDS (staged once) + per-tap A dbuf, 16 waves/CU ---------
// grid (14 rg, 32 n, 2 ktb) = 896 blocks, 512 threads = 8 waves.
// Block: 128 out-ch x 4 output rows. Wave (wr=row 0..3, wh=ch-half 0..1):
// 64 ch x 64 px, acc[2][2] = 64 VGPR. Per ks: 2 A + 2 B LDS b128 -> 4 MFMA.
__global__ __launch_bounds__(512, 4) void conv_kernel(const int8_t* __restrict__ xp,
                                                      const int8_t* __restrict__ wq,
                                                      const int* __restrict__ bias,
                                                      const float* __restrict__ wscale,
                                                      int* __restrict__ out) {
  __shared__ __align__(16) int8_t lw[2][8 * 128 * 16];        // 2 x 16,384 B
  __shared__ __align__(16) int8_t lx[(6 * HP + 8) * 8 * 16];  // 45,568 B (+pad)
  __shared__ int   bsh[128];
  __shared__ float ssh[128];

  const int tid = threadIdx.x;
  const int rg = blockIdx.x;           // row group 0..13
  const int n_img = blockIdx.y;
  const int ktb = blockIdx.z;          // 128-ch slice, slowest -> L2 reuse of xp
  const int h0 = rg * 4;

  const int lane = tid & 63;
  const int wid = tid >> 6;            // wave 0..7
  const int wr = wid & 3;              // output row
  const int wh = wid >> 2;             // 64-ch half
  const int p0 = lane & 31;
  const int half = lane >> 5;

  const int8_t* xg = xp + ((size_t)(n_img * HP) + h0) * ROWB;
  const int8_t* wqt = wq + (size_t)ktb * (9 * 16384);

  // ---- stage pixels: 6 padded rows = 2784 chunks, XOR swizzle in source ----
  #pragma unroll
  for (int it = 0; it < 6; ++it) {
    const int i = it * 512 + tid;
    if (i < 6 * HP * 8) {
      const int pf = i >> 3;
      const int cc = (i & 7) ^ (pf & 7);
      gload_lds16(xg + pf * CIN + (cc << 4), lx + i * 16);
    }
  }
  // ---- stage weights tap 0: 1024 chunks ----
  gload_lds16(wqt + tid * 16, lw[0] + tid * 16);
  gload_lds16(wqt + (512 + tid) * 16, lw[0] + (512 + tid) * 16);
  if (tid < 128) {
    const int ch = ktb * 128 + tid;
    bsh[tid] = bias[ch];
    ssh[tid] = (0.02f * wscale[ch]) / 0.05f;   // IN_SCALE * ws / OUT_SCALE
  }
  __syncthreads();

  v16i acc[2][2];                      // [mt: 32-ch tile][nt: 32-px tile]
  #pragma unroll
  for (int mt = 0; mt < 2; ++mt)
    #pragma unroll
    for (int nt = 0; nt < 2; ++nt)
      #pragma unroll
      for (int e = 0; e < 16; ++e) acc[mt][nt][e] = 0;

  const int chb = wh * 64;             // this wave's 64-ch half

  #pragma unroll
  for (int tap = 0; tap < 9; ++tap) {
    // prefetch next tap's weights into the other buffer (drained at barrier)
    if (tap < 8) {
      const int8_t* wsrc = wqt + (tap + 1) * 16384;
      int8_t* ldst = lw[(tap + 1) & 1];
      gload_lds16(wsrc + tid * 16, ldst + tid * 16);
      gload_lds16(wsrc + (512 + tid) * 16, ldst + (512 + tid) * 16);
    }
    const int kh = (tap >= 3) + (tap >= 6);
    const int kw = tap - 3 * kh;
    const int8_t* lwt = lw[tap & 1];             // [cc(8)][ch(128)] chunk-major
    const int pfb = (wr + kh) * HP + kw;
    #pragma unroll
    for (int ks = 0; ks < 4; ++ks) {
      const int cch = 2 * ks + half;             // k-chunk for this lane
      const v4i a0 = *reinterpret_cast<const v4i*>(lwt + cch * 2048 + (chb + p0) * 16);
      const v4i a1 = *reinterpret_cast<const v4i*>(lwt + cch * 2048 + (chb + 32 + p0) * 16);
      const int pf0 = pfb + p0;
      const int pf1 = pfb + 32 + p0;
      const v4i b0 = *reinterpret_cast<const v4i*>(lx + pf0 * CIN + ((cch ^ (pf0 & 7)) << 4));
      const v4i b1 = *reinterpret_cast<const v4i*>(lx + pf1 * CIN + ((cch ^ (pf1 & 7)) << 4));
      // edge reads (col>57) land in the lx pad; they feed only masked w>=56.
      __builtin_amdgcn_s_setprio(1);
      acc[0][0] = __builtin_amdgcn_mfma_i32_32x32x32_i8(a0, b0, acc[0][0], 0, 0, 0);
      acc[1][0] = __builtin_amdgcn_mfma_i32_32x32x32_i8(a1, b0, acc[1][0], 0, 0, 0);
      acc[0][1] = __builtin_amdgcn_mfma_i32_32x32x32_i8(a0, b1, acc[0][1], 0, 0, 0);
      acc[1][1] = __builtin_amdgcn_mfma_i32_32x32x32_i8(a1, b1, acc[1][1], 0, 0, 0);
      __builtin_amdgcn_s_setprio(0);
    }
    __syncthreads();                   // drains prefetch; guards dbuf swap
  }

  // ---- epilogue: D row = ch = mt*32 + (r&3)+8*(r>>2)+4*half, col = pixel ----
  const int h = h0 + wr;
  #pragma unroll
  for (int mt = 0; mt < 2; ++mt) {
    #pragma unroll
    for (int r = 0; r < 16; ++r) {
      const int cl = chb + mt * 32 + (r & 3) + 8 * (r >> 2) + 4 * half;
      const int bi = bsh[cl];
      const float sc = ssh[cl];
      int* ob = out + (((size_t)(n_img * KOUT + ktb * 128 + cl)) * HO + h) * WO;
      #pragma unroll
      for (int nt = 0; nt < 2; ++nt) {
        const int w = nt * 32 + p0;
        if (w < WO) {
          float v = (float)(acc[mt][nt][r] + bi) * sc;
          v = rintf(v);                          // round-half-even == jnp.round
          v = fminf(fmaxf(v, -128.0f), 127.0f);
          ob[w] = (int)v;
        }
      }
    }
  }
}

extern "C" void kernel_launch(void* const* d_in, const int* in_sizes, int n_in,
                              void* d_out, int out_size, void* d_ws, size_t ws_size,
                              hipStream_t stream) {
  const int* x = (const int*)d_in[0];
  const int* wgt = (const int*)d_in[1];
  const int* bias = (const int*)d_in[2];
  const float* wscale = (const float*)d_in[3];
  int* out = (int*)d_out;

  int8_t* xp = (int8_t*)d_ws;                               // 13,780,992 B
  int8_t* wq = (int8_t*)d_ws + (size_t)NB * HP * ROWB;      // 294,912 B

  pack_x_kernel<<<dim3(HP, NB), 256, 0, stream>>>(x, xp);
  pack_w_kernel<<<288, 256, 0, stream>>>(wgt, wq);
  conv_kernel<<<dim3(14, 32, 2), 512, 0, stream>>>(xp, wq, bias, wscale, out);
}